// Round 7
// baseline (297.370 us; speedup 1.0000x reference)
//
#include <hip/hip_runtime.h>
#include <math.h>

// Problem constants
#define Bn   32
#define Cn   684
#define Hn   16
#define Wn   64
#define HWn  1024
#define HIDn 256
#define An   512
#define KKn  121           // 11*11
#define CREAL 805          // 684 + 121
#define CPAD 832           // 26 chunks of 32 (row stride of Xt and VTbf)
#define NSTEP 26

// Output layout (flat fp32): context [32,684] | alpha [32,1024] | alpha_sum_new [32,1024]
#define OUT_ALPHA 21888
#define OUT_ASUM  (21888 + 32768)

typedef short short8 __attribute__((ext_vector_type(8)));     // 8 bf16 = 4 VGPRs
typedef float floatx4 __attribute__((ext_vector_type(4)));    // MFMA acc

__device__ __forceinline__ float bf2f(unsigned short u) {
    union { unsigned int i; float f; } v; v.i = ((unsigned int)u) << 16; return v.f;
}
__device__ __forceinline__ unsigned short f2bf(float f) {
    union { float f; unsigned int i; } v; v.f = f;
    unsigned int i = v.i;
    return (unsigned short)((i + 0x7fffu + ((i >> 16) & 1u)) >> 16);
}
__device__ __forceinline__ unsigned int pack2bf(float v0, float v1) {
    unsigned int u0 = __float_as_uint(v0), u1 = __float_as_uint(v1);
    u0 = (u0 + 0x7fffu + ((u0 >> 16) & 1u)) >> 16;
    u1 = (u1 + 0x7fffu + ((u1 >> 16) & 1u)) & 0xffff0000u;
    return u0 | u1;
}

// ---------------------------------------------------------------------------
// K_prep: three block families in one launch.
//   blocks 0..511     : transpose  Xt[b][hw][c'] bf16  (im2col rows baked in)
//   blocks 512..1023  : build VTbf row a  (k-contiguous)
//   blocks 1024..1055 : query[b,a] = bh[a]+bec[a]+hidden[b]·Wh[a]
__global__ __launch_bounds__(256) void k_prep(
    const float* __restrict__ X,
    const float* __restrict__ asum,
    const float* __restrict__ hidden,
    const float* __restrict__ Wh,
    const float* __restrict__ bh,
    const float* __restrict__ bec,
    const float* __restrict__ Wec,
    const float* __restrict__ Wac,
    const float* __restrict__ Waw,
    float* __restrict__ query,
    unsigned short* __restrict__ VTbf,
    unsigned short* __restrict__ Xt)
{
    __shared__ float sbuf[512];
    __shared__ float wac_s[64 * KKn];   // 31 KB k-chunk of Wac
    __shared__ float plane[11 * 74 + 2];
    const int blk = blockIdx.x, t = threadIdx.x;

    if (blk < 512) {
        // ---- transpose branch: block = (b, h-row); 64 pos x 832 c'
        const int b = blk >> 4, h = blk & 15;
        for (int i = t; i < 11 * 74; i += 256) {
            int di = i / 74, cc = i - di * 74;
            int h2 = h + di - 5, w2 = cc - 5;
            float v = 0.f;
            if (h2 >= 0 && h2 < Hn && w2 >= 0 && w2 < Wn)
                v = asum[b * HWn + h2 * Wn + w2];
            plane[i] = v;
        }
        __syncthreads();
        const int m = t >> 2, cq = t & 3;
        const float* Xbh = X + (size_t)b * Cn * HWn + h * Wn;   // + c*HWn + m
        unsigned short* Xr = Xt + (size_t)(b * HWn + h * Wn + m) * CPAD;
        for (int cb = 0; cb < NSTEP; ++cb) {
            const int c0 = cb * 32 + cq * 8;
            float v[8];
            if (c0 + 7 < Cn) {
                #pragma unroll
                for (int j = 0; j < 8; ++j)
                    v[j] = Xbh[(size_t)(c0 + j) * HWn + m];
            } else {
                #pragma unroll
                for (int j = 0; j < 8; ++j) {
                    int c = c0 + j;
                    float x;
                    if (c < Cn) x = Xbh[(size_t)c * HWn + m];
                    else if (c < CREAL) {
                        int ij = c - Cn; int di = ij / 11, dj = ij - di * 11;
                        x = plane[di * 74 + m + dj];
                    } else x = 0.f;
                    v[j] = x;
                }
            }
            unsigned int pk[4];
            #pragma unroll
            for (int j = 0; j < 4; ++j) pk[j] = pack2bf(v[2 * j], v[2 * j + 1]);
            *(uint4*)(Xr + c0) = make_uint4(pk[0], pk[1], pk[2], pk[3]);
        }
    } else if (blk < 1024) {
        // ---- VTbf branch
        const int a = blk - 512;
        sbuf[t]       = Waw[(size_t)a * 512 + t];
        sbuf[t + 256] = Waw[(size_t)a * 512 + t + 256];
        for (int cp = t; cp < Cn; cp += 256)
            VTbf[(size_t)a * CPAD + cp] = f2bf(Wec[(size_t)a * Cn + cp]);
        float s = 0.f;
        for (int kb = 0; kb < 8; ++kb) {
            __syncthreads();
            for (int i = t; i < 64 * KKn; i += 256)
                wac_s[i] = Wac[kb * 64 * KKn + i];     // coalesced
            __syncthreads();
            if (t < KKn) {
                #pragma unroll 8
                for (int kk = 0; kk < 64; ++kk)
                    s = fmaf(sbuf[kb * 64 + kk], wac_s[kk * KKn + t], s);
            }
        }
        if (t < KKn)
            VTbf[(size_t)a * CPAD + Cn + t] = f2bf(s);
        for (int cp = CREAL + t; cp < CPAD; cp += 256)
            VTbf[(size_t)a * CPAD + cp] = 0;
    } else {
        // ---- query branch
        const int b = blk - 1024;
        sbuf[t] = (t < HIDn) ? hidden[b * HIDn + t] : 0.f;
        __syncthreads();
        for (int a = t; a < An; a += 256) {
            const float4* wp = (const float4*)(Wh + (size_t)a * HIDn);
            float s = bh[a] + bec[a];
            #pragma unroll 8
            for (int i = 0; i < HIDn / 4; ++i) {
                float4 w = wp[i];
                s = fmaf(sbuf[4 * i],     w.x, s);
                s = fmaf(sbuf[4 * i + 1], w.y, s);
                s = fmaf(sbuf[4 * i + 2], w.z, s);
                s = fmaf(sbuf[4 * i + 3], w.w, s);
            }
            query[b * An + a] = s;
        }
    }
}

// ---------------------------------------------------------------------------
// K_energy v7: barrier-free, LDS-free main loop. Block = (b,hh): M=64, N=512,
// K=832. Wave owns 128-a panel: 4x8 frags, 32 MFMA / K-chunk. A and B frags
// load DIRECTLY from bf16 k-contiguous global (Xt L1/L2, VTbf L2-resident).
__global__ __launch_bounds__(256, 2) void k_energy(
    const unsigned short* __restrict__ Xt,
    const float* __restrict__ Wv,
    const float* __restrict__ query,
    const unsigned short* __restrict__ VTbf,
    float* __restrict__ energy)
{
    __shared__ float red[64 * 65];
    __shared__ float qs[An];
    __shared__ float wvs[An];

    const int t = threadIdx.x;
    const int hh = blockIdx.x, b = blockIdx.y;
    const int w = t >> 6, lane = t & 63;
    const int q = lane >> 4, r = lane & 15;

    qs[t]        = query[b * An + t];
    qs[t + 256]  = query[b * An + t + 256];
    wvs[t]       = Wv[t];
    wvs[t + 256] = Wv[t + 256];

    const unsigned short* Arow = Xt + (size_t)(b * HWn + hh * Wn) * CPAD + r * CPAD + q * 8;
    const unsigned short* Brow = VTbf + (size_t)(w * 128) * CPAD + r * CPAD + q * 8;

    floatx4 acc[4][8];
    #pragma unroll
    for (int mf = 0; mf < 4; ++mf)
        #pragma unroll
        for (int nf = 0; nf < 8; ++nf)
            acc[mf][nf] = (floatx4){0.f, 0.f, 0.f, 0.f};

    short8 af[4], bfA[8], bfB[8];
    #pragma unroll
    for (int nf = 0; nf < 8; ++nf)
        bfA[nf] = *(const short8*)(Brow + (size_t)(nf * 16) * CPAD);

    for (int ch = 0; ch < NSTEP; ch += 2) {
        const int c0 = ch * 32;
        // chunk ch: A loads, B prefetch for ch+1, MFMA
        #pragma unroll
        for (int mf = 0; mf < 4; ++mf)
            af[mf] = *(const short8*)(Arow + (size_t)(mf * 16) * CPAD + c0);
        #pragma unroll
        for (int nf = 0; nf < 8; ++nf)
            bfB[nf] = *(const short8*)(Brow + (size_t)(nf * 16) * CPAD + c0 + 32);
        #pragma unroll
        for (int mf = 0; mf < 4; ++mf)
            #pragma unroll
            for (int nf = 0; nf < 8; ++nf)
                acc[mf][nf] = __builtin_amdgcn_mfma_f32_16x16x32_bf16(
                    af[mf], bfA[nf], acc[mf][nf], 0, 0, 0);
        // chunk ch+1: A loads, B prefetch for ch+2, MFMA
        #pragma unroll
        for (int mf = 0; mf < 4; ++mf)
            af[mf] = *(const short8*)(Arow + (size_t)(mf * 16) * CPAD + c0 + 32);
        if (ch + 2 < NSTEP) {
            #pragma unroll
            for (int nf = 0; nf < 8; ++nf)
                bfA[nf] = *(const short8*)(Brow + (size_t)(nf * 16) * CPAD + c0 + 64);
        }
        #pragma unroll
        for (int mf = 0; mf < 4; ++mf)
            #pragma unroll
            for (int nf = 0; nf < 8; ++nf)
                acc[mf][nf] = __builtin_amdgcn_mfma_f32_16x16x32_bf16(
                    af[mf], bfB[nf], acc[mf][nf], 0, 0, 0);
    }

    // ---- epilogue: e[m] = sum_n Wv[n]*tanh(acc + query[n])
    float ep[16];
    #pragma unroll
    for (int i = 0; i < 16; ++i) ep[i] = 0.f;
    #pragma unroll
    for (int nf = 0; nf < 8; ++nf) {
        int n = w * 128 + nf * 16 + r;
        float qv = qs[n], wv = wvs[n];
        #pragma unroll
        for (int mf = 0; mf < 4; ++mf)
            #pragma unroll
            for (int rg = 0; rg < 4; ++rg) {
                float x = acc[mf][nf][rg] + qv;
                float e2 = __expf(2.f * x);
                float th = 1.f - 2.f * __builtin_amdgcn_rcpf(e2 + 1.f);
                ep[mf * 4 + rg] += wv * th;
            }
    }
    __syncthreads();
    #pragma unroll
    for (int mf = 0; mf < 4; ++mf)
        #pragma unroll
        for (int rg = 0; rg < 4; ++rg)
            red[(mf * 16 + q * 4 + rg) * 65 + w * 16 + r] = ep[mf * 4 + rg];
    __syncthreads();
    if (t < 64) {
        float s = 0.f;
        #pragma unroll 16
        for (int i = 0; i < 64; ++i) s += red[t * 65 + i];
        energy[b * HWn + hh * Wn + t] = s;
    }
}

// ---------------------------------------------------------------------------
// K_ctx: fused softmax + context from Xt. Grid (16 hw-chunks, 32 b).
// Each block: full softmax recompute (1024 energies), then context partials
// for its 64-hw slice over all 684 channels (c-pairs per thread, atomicAdd).
// Block hhc==0 writes alpha / alpha_sum_new.
__global__ __launch_bounds__(256) void k_ctx(
    const unsigned short* __restrict__ Xt,
    const float* __restrict__ energy,
    const float* __restrict__ mask,
    const float* __restrict__ asum,
    float* __restrict__ out)
{
    __shared__ float al[1024];
    __shared__ float rsm[8];
    const int hhc = blockIdx.x, b = blockIdx.y;
    const int t = threadIdx.x, lane = t & 63, wid = t >> 6;

    float e[4], ex[4];
    #pragma unroll
    for (int i = 0; i < 4; ++i) e[i] = energy[b * HWn + i * 256 + t];
    float m = fmaxf(fmaxf(e[0], e[1]), fmaxf(e[2], e[3]));
    for (int off = 32; off >= 1; off >>= 1) m = fmaxf(m, __shfl_down(m, off, 64));
    if (lane == 0) rsm[wid] = m;
    __syncthreads();
    if (t == 0) rsm[4] = fmaxf(fmaxf(rsm[0], rsm[1]), fmaxf(rsm[2], rsm[3]));
    __syncthreads();
    const float M = rsm[4];
    float s = 0.f;
    #pragma unroll
    for (int i = 0; i < 4; ++i) {
        ex[i] = expf(e[i] - M) * mask[b * HWn + i * 256 + t];
        s += ex[i];
    }
    for (int off = 32; off >= 1; off >>= 1) s += __shfl_down(s, off, 64);
    __syncthreads();
    if (lane == 0) rsm[wid] = s;
    __syncthreads();
    if (t == 0) rsm[5] = rsm[0] + rsm[1] + rsm[2] + rsm[3] + 1e-10f;
    __syncthreads();
    const float denom = rsm[5];
    #pragma unroll
    for (int i = 0; i < 4; ++i) al[i * 256 + t] = ex[i] / denom;
    __syncthreads();

    // context partials: thread owns c-pairs d and d+256 (684 c = 342 dwords)
    float c0a = 0.f, c0b = 0.f, c1a = 0.f, c1b = 0.f;
    const int d0 = t, d1 = t + 256;
    const unsigned int* Xr =
        (const unsigned int*)(Xt + (size_t)(b * HWn + hhc * 64) * CPAD);
    for (int hl = 0; hl < 64; ++hl) {
        const float a = al[hhc * 64 + hl];
        const unsigned int* row = Xr + (size_t)hl * (CPAD / 2);
        unsigned int u0 = row[d0];
        c0a = fmaf(a, bf2f((unsigned short)(u0 & 0xffffu)), c0a);
        c0b = fmaf(a, bf2f((unsigned short)(u0 >> 16)),     c0b);
        if (d1 < 342) {
            unsigned int u1 = row[d1];
            c1a = fmaf(a, bf2f((unsigned short)(u1 & 0xffffu)), c1a);
            c1b = fmaf(a, bf2f((unsigned short)(u1 >> 16)),     c1b);
        }
    }
    atomicAdd(&out[b * Cn + 2 * d0],     c0a);
    atomicAdd(&out[b * Cn + 2 * d0 + 1], c0b);
    if (d1 < 342) {
        atomicAdd(&out[b * Cn + 2 * d1],     c1a);
        atomicAdd(&out[b * Cn + 2 * d1 + 1], c1b);
    }

    if (hhc == 0) {
        #pragma unroll
        for (int i = 0; i < 4; ++i) {
            int p = i * 256 + t;
            float a = al[p];
            out[OUT_ALPHA + b * HWn + p] = a;
            out[OUT_ASUM  + b * HWn + p] = a + asum[b * HWn + p];
        }
    }
}

// ---------------------------------------------------------------------------
extern "C" void kernel_launch(void* const* d_in, const int* in_sizes, int n_in,
                              void* d_out, int out_size, void* d_ws, size_t ws_size,
                              hipStream_t stream)
{
    const float* X      = (const float*)d_in[0];
    const float* hidden = (const float*)d_in[1];
    const float* asum   = (const float*)d_in[2];
    const float* mask   = (const float*)d_in[3];
    const float* Wh     = (const float*)d_in[4];
    const float* bh     = (const float*)d_in[5];
    const float* Wec    = (const float*)d_in[6];
    const float* bec    = (const float*)d_in[7];
    const float* Wac    = (const float*)d_in[8];
    const float* Waw    = (const float*)d_in[9];
    const float* Wv     = (const float*)d_in[10];
    (void)in_sizes; (void)n_in; (void)out_size; (void)ws_size;

    float* out = (float*)d_out;
    // ws layout (16B-aligned base): Xt | VTbf | query | energy
    unsigned short* Xt   = (unsigned short*)d_ws;            // 32*1024*832
    unsigned short* VTbf = Xt + (size_t)Bn * HWn * CPAD;     // 512*832
    float* query  = (float*)(VTbf + (size_t)An * CPAD);      // 16384
    float* energy = query + 16384;                           // 32768

    hipMemsetAsync(out, 0, OUT_ALPHA * sizeof(float), stream);  // context accum
    k_prep   <<<dim3(1056),   dim3(256), 0, stream>>>(X, asum, hidden, Wh, bh, bec,
                                                      Wec, Wac, Waw, query, VTbf, Xt);
    k_energy <<<dim3(16, 32), dim3(256), 0, stream>>>(Xt, Wv, query, VTbf, energy);
    k_ctx    <<<dim3(16, 32), dim3(256), 0, stream>>>(Xt, energy, mask, asum, out);
}